// Round 3
// baseline (9481.010 us; speedup 1.0000x reference)
//
#include <hip/hip_runtime.h>
#include <hip/hip_bf16.h>

// ---------------------------------------------------------------------------
// ViTChess: 6-layer transformer block stack, B=512 N=65 C=768 H=12 DH=64
// bf16 MFMA GEMMs (32x32x16), fp32 accum, residual stream lives in d_out.
// R3: occupancy 5 blk/CU on gemm_bt, fused gate*silu(value) MLP GEMM,
//     bijective XCD block remap, batched weight transposes.
// ---------------------------------------------------------------------------

typedef __bf16 v8bf  __attribute__((ext_vector_type(8)));
typedef __bf16 v4bf  __attribute__((ext_vector_type(4)));
typedef float  v16f  __attribute__((ext_vector_type(16)));

#define EPI_BF16      0
#define EPI_ADDF32    1
#define EPI_SILU      2
#define EPI_MUL       3
#define EPI_BF16MASK  4

__device__ __forceinline__ v16f mfma32(v8bf a, v8bf b, v16f c) {
  return __builtin_amdgcn_mfma_f32_32x32x16_bf16(a, b, c, 0, 0, 0);
}

// Bijective XCD-aware remap (m204): dispatch round-robins id%8 across XCDs;
// give each XCD a contiguous chunk of x-major tile space for L2 locality.
__device__ __forceinline__ void xcd_remap(int& bx, int& by) {
  const int gx = gridDim.x;
  const int nwg = gx * gridDim.y;
  int id = by * gx + bx;
  int q = nwg >> 3, r = nwg & 7;
  int xcd = id & 7, pos = id >> 3;
  int nid = (xcd < r ? xcd * (q + 1) : r * (q + 1) + (xcd - r) * q) + pos;
  bx = nid % gx; by = nid / gx;
}

// C[M,N] = A[M,K] @ Bt[N,K]^T.  M%128==0, N%128==0 (padded), K%64==0.
// LDS tiles 128x64 bf16, 16B chunks XOR-swizzled by (row&7). 5 blocks/CU.
template<int EPI>
__global__ __launch_bounds__(256, 5)
void gemm_bt(const __bf16* __restrict__ A, long long lda,
             const __bf16* __restrict__ Bt,
             void* outp, const __bf16* extra,
             int Nout, int K, int nvalid)
{
  __shared__ __align__(16) __bf16 Als[128 * 64];
  __shared__ __align__(16) __bf16 Bls[128 * 64];
  const int tid  = threadIdx.x;
  const int w    = tid >> 6, lane = tid & 63;
  int bx = blockIdx.x, by = blockIdx.y;
  xcd_remap(bx, by);
  const int m0   = by * 128, n0 = bx * 128;
  const int wm   = (w & 1) * 64, wn = (w >> 1) * 64;
  const int l31  = lane & 31, l5 = lane >> 5;

  const __bf16* ag[4];
  const __bf16* bg[4];
#pragma unroll
  for (int i = 0; i < 4; ++i) {
    int li  = i * 256 + tid;
    int row = li >> 3;
    int c   = (li & 7) ^ (row & 7);           // swizzled source chunk
    ag[i] = A  + (size_t)(m0 + row) * (size_t)lda + c * 8;
    bg[i] = Bt + (size_t)(n0 + row) * (size_t)K   + c * 8;
  }
  char* alds0 = ((char*)Als) + w * 1024;
  char* blds0 = ((char*)Bls) + w * 1024;

  v16f acc[2][2] = {};

  for (int kt = 0; kt < K; kt += 64) {
#pragma unroll
    for (int i = 0; i < 4; ++i) {
      __builtin_amdgcn_global_load_lds(
          (const __attribute__((address_space(1))) void*)(ag[i]),
          (__attribute__((address_space(3))) void*)(alds0 + i * 4096), 16, 0, 0);
      __builtin_amdgcn_global_load_lds(
          (const __attribute__((address_space(1))) void*)(bg[i]),
          (__attribute__((address_space(3))) void*)(blds0 + i * 4096), 16, 0, 0);
      ag[i] += 64; bg[i] += 64;
    }
    __syncthreads();
#pragma unroll
    for (int kk = 0; kk < 4; ++kk) {
      v8bf af[2], bf[2];
#pragma unroll
      for (int t = 0; t < 2; ++t) {
        int m  = wm + t * 32 + l31;
        int ch = (kk * 2 + l5) ^ (m & 7);
        af[t] = *(const v8bf*)(Als + m * 64 + ch * 8);
        int n   = wn + t * 32 + l31;
        int ch2 = (kk * 2 + l5) ^ (n & 7);
        bf[t] = *(const v8bf*)(Bls + n * 64 + ch2 * 8);
      }
      acc[0][0] = mfma32(af[0], bf[0], acc[0][0]);
      acc[0][1] = mfma32(af[0], bf[1], acc[0][1]);
      acc[1][0] = mfma32(af[1], bf[0], acc[1][0]);
      acc[1][1] = mfma32(af[1], bf[1], acc[1][1]);
    }
    __syncthreads();
  }

  // D layout: col = lane&31, row = (r&3) + 8*(r>>2) + 4*(lane>>5)
#pragma unroll
  for (int mi = 0; mi < 2; ++mi)
#pragma unroll
  for (int ni = 0; ni < 2; ++ni) {
    int col  = n0 + wn + ni * 32 + l31;
    int rowb = m0 + wm + mi * 32 + 4 * l5;
#pragma unroll
    for (int r = 0; r < 16; ++r) {
      int row   = rowb + (r & 3) + 8 * (r >> 2);
      float val = acc[mi][ni][r];
      size_t idx = (size_t)row * (size_t)Nout + col;
      if (EPI == EPI_BF16) {
        ((__bf16*)outp)[idx] = (__bf16)val;
      } else if (EPI == EPI_ADDF32) {
        ((float*)outp)[idx] += val;
      } else if (EPI == EPI_SILU) {
        float s = val / (1.f + __expf(-val));
        ((__bf16*)outp)[idx] = (__bf16)s;
      } else if (EPI == EPI_MUL) {
        float e = (float)extra[idx];
        ((__bf16*)outp)[idx] = (__bf16)(val * e);
      } else { // EPI_BF16MASK: output compacted to stride (nvalid+7)&~7
        int stride = (nvalid + 7) & ~7;
        if (col < nvalid)
          ((__bf16*)outp)[(size_t)row * (size_t)stride + col] = (__bf16)val;
      }
    }
  }
}

// Fused MLP: out[M,N] = silu(A@Bv^T) * (A@Bg^T), bf16 out. A staged once.
// LDS 48KB -> 3 blocks/CU.
__global__ __launch_bounds__(256, 3)
void gemm_mlp(const __bf16* __restrict__ A,
              const __bf16* __restrict__ Bv, const __bf16* __restrict__ Bg,
              __bf16* __restrict__ outp, int Nout, int K)
{
  __shared__ __align__(16) __bf16 Als [128 * 64];
  __shared__ __align__(16) __bf16 Bvls[128 * 64];
  __shared__ __align__(16) __bf16 Bgls[128 * 64];
  const int tid  = threadIdx.x;
  const int w    = tid >> 6, lane = tid & 63;
  int bx = blockIdx.x, by = blockIdx.y;
  xcd_remap(bx, by);
  const int m0   = by * 128, n0 = bx * 128;
  const int wm   = (w & 1) * 64, wn = (w >> 1) * 64;
  const int l31  = lane & 31, l5 = lane >> 5;

  const __bf16* ag[4];
  const __bf16* bvg[4];
  const __bf16* bgg[4];
#pragma unroll
  for (int i = 0; i < 4; ++i) {
    int li  = i * 256 + tid;
    int row = li >> 3;
    int c   = (li & 7) ^ (row & 7);
    ag[i]  = A  + (size_t)(m0 + row) * (size_t)K + c * 8;
    bvg[i] = Bv + (size_t)(n0 + row) * (size_t)K + c * 8;
    bgg[i] = Bg + (size_t)(n0 + row) * (size_t)K + c * 8;
  }
  char* alds0  = ((char*)Als)  + w * 1024;
  char* bvlds0 = ((char*)Bvls) + w * 1024;
  char* bglds0 = ((char*)Bgls) + w * 1024;

  v16f accv[2][2] = {};
  v16f accg[2][2] = {};

  for (int kt = 0; kt < K; kt += 64) {
#pragma unroll
    for (int i = 0; i < 4; ++i) {
      __builtin_amdgcn_global_load_lds(
          (const __attribute__((address_space(1))) void*)(ag[i]),
          (__attribute__((address_space(3))) void*)(alds0 + i * 4096), 16, 0, 0);
      __builtin_amdgcn_global_load_lds(
          (const __attribute__((address_space(1))) void*)(bvg[i]),
          (__attribute__((address_space(3))) void*)(bvlds0 + i * 4096), 16, 0, 0);
      __builtin_amdgcn_global_load_lds(
          (const __attribute__((address_space(1))) void*)(bgg[i]),
          (__attribute__((address_space(3))) void*)(bglds0 + i * 4096), 16, 0, 0);
      ag[i] += 64; bvg[i] += 64; bgg[i] += 64;
    }
    __syncthreads();
#pragma unroll
    for (int kk = 0; kk < 4; ++kk) {
      v8bf af[2], bv[2], bg2[2];
#pragma unroll
      for (int t = 0; t < 2; ++t) {
        int m  = wm + t * 32 + l31;
        int ch = (kk * 2 + l5) ^ (m & 7);
        af[t] = *(const v8bf*)(Als + m * 64 + ch * 8);
        int n   = wn + t * 32 + l31;
        int ch2 = (kk * 2 + l5) ^ (n & 7);
        bv[t]  = *(const v8bf*)(Bvls + n * 64 + ch2 * 8);
        bg2[t] = *(const v8bf*)(Bgls + n * 64 + ch2 * 8);
      }
      accv[0][0] = mfma32(af[0], bv[0],  accv[0][0]);
      accg[0][0] = mfma32(af[0], bg2[0], accg[0][0]);
      accv[0][1] = mfma32(af[0], bv[1],  accv[0][1]);
      accg[0][1] = mfma32(af[0], bg2[1], accg[0][1]);
      accv[1][0] = mfma32(af[1], bv[0],  accv[1][0]);
      accg[1][0] = mfma32(af[1], bg2[0], accg[1][0]);
      accv[1][1] = mfma32(af[1], bv[1],  accv[1][1]);
      accg[1][1] = mfma32(af[1], bg2[1], accg[1][1]);
    }
    __syncthreads();
  }

#pragma unroll
  for (int mi = 0; mi < 2; ++mi)
#pragma unroll
  for (int ni = 0; ni < 2; ++ni) {
    int col  = n0 + wn + ni * 32 + l31;
    int rowb = m0 + wm + mi * 32 + 4 * l5;
#pragma unroll
    for (int r = 0; r < 16; ++r) {
      int row = rowb + (r & 3) + 8 * (r >> 2);
      float v = accv[mi][ni][r];
      float g = accg[mi][ni][r];
      float s = v / (1.f + __expf(-v)) * g;
      outp[(size_t)row * (size_t)Nout + col] = (__bf16)s;
    }
  }
}

// Batched fp32 (K,N) -> bf16 (Npad,K) transpose; 8 segments in one launch.
struct TBatch {
  const float* src[8];
  __bf16* dst[8];
  int K[8], N[8], Npad[8], gx[8], blk0[8];
};

__global__ void transpose_batched(TBatch tb)
{
  __shared__ float t[32][33];
  int id = blockIdx.x;
  int s = 0;
#pragma unroll
  for (int i = 1; i < 8; ++i) if (id >= tb.blk0[i]) s = i;
  const float* src = tb.src[s];
  __bf16* dst = tb.dst[s];
  const int K = tb.K[s], N = tb.N[s], Npad = tb.Npad[s];
  int local = id - tb.blk0[s];
  int bx = local % tb.gx[s], by = local / tb.gx[s];
  int n0 = bx * 32, k0 = by * 32;
  int tx = threadIdx.x, ty = threadIdx.y;
#pragma unroll
  for (int i = 0; i < 32; i += 8) {
    int k = k0 + ty + i, n = n0 + tx;
    t[ty + i][tx] = (k < K && n < N) ? src[(size_t)k * N + n] : 0.f;
  }
  __syncthreads();
#pragma unroll
  for (int i = 0; i < 32; i += 8) {
    int n = n0 + ty + i, k = k0 + tx;
    if (n < Npad && k < K) dst[(size_t)n * K + k] = (__bf16)t[tx][ty + i];
  }
}

// row LN fp32->bf16, C=768, one wave per row, 4 rows per block (float4 loads)
__global__ __launch_bounds__(256)
void ln768_f32_to_bf16(const float* __restrict__ x, const float* __restrict__ g,
                       const float* __restrict__ bb, __bf16* __restrict__ out)
{
  const int row  = blockIdx.x * 4 + (threadIdx.x >> 6);
  const int lane = threadIdx.x & 63;
  const float* xr = x + (size_t)row * 768;
  float4 v[3];
  float sum = 0.f, sq = 0.f;
#pragma unroll
  for (int c = 0; c < 3; ++c) {
    v[c] = *(const float4*)(xr + c * 256 + lane * 4);
    sum += v[c].x + v[c].y + v[c].z + v[c].w;
    sq  += v[c].x * v[c].x + v[c].y * v[c].y + v[c].z * v[c].z + v[c].w * v[c].w;
  }
#pragma unroll
  for (int d = 1; d < 64; d <<= 1) { sum += __shfl_xor(sum, d); sq += __shfl_xor(sq, d); }
  float mean = sum * (1.f / 768.f);
  float var  = sq * (1.f / 768.f) - mean * mean;
  float rs   = rsqrtf(var + 1e-5f);
  __bf16* orow = out + (size_t)row * 768;
#pragma unroll
  for (int c = 0; c < 3; ++c) {
    float4 gv = *(const float4*)(g  + c * 256 + lane * 4);
    float4 bv = *(const float4*)(bb + c * 256 + lane * 4);
    v4bf o4;
    o4[0] = (__bf16)((v[c].x - mean) * rs * gv.x + bv.x);
    o4[1] = (__bf16)((v[c].y - mean) * rs * gv.y + bv.y);
    o4[2] = (__bf16)((v[c].z - mean) * rs * gv.z + bv.z);
    o4[3] = (__bf16)((v[c].w - mean) * rs * gv.w + bv.w);
    *(v4bf*)(orow + c * 256 + lane * 4) = o4;
  }
}

// row LN on bf16 input, optional silu (cls path, small)
__global__ __launch_bounds__(256)
void ln_bf16_kernel(const __bf16* __restrict__ x, const float* __restrict__ g,
                    const float* __restrict__ bb, __bf16* __restrict__ out,
                    int C, int do_silu)
{
  __shared__ float sm[8];
  const __bf16* xr = x + (size_t)blockIdx.x * C;
  float sum = 0.f, sq = 0.f;
  for (int i = threadIdx.x; i < C; i += 256) { float v = (float)xr[i]; sum += v; sq += v * v; }
#pragma unroll
  for (int d = 1; d < 64; d <<= 1) { sum += __shfl_xor(sum, d); sq += __shfl_xor(sq, d); }
  if ((threadIdx.x & 63) == 0) { sm[threadIdx.x >> 6] = sum; sm[4 + (threadIdx.x >> 6)] = sq; }
  __syncthreads();
  sum = sm[0] + sm[1] + sm[2] + sm[3];
  sq  = sm[4] + sm[5] + sm[6] + sm[7];
  float mean = sum / C;
  float var  = sq / C - mean * mean;
  float rs   = rsqrtf(var + 1e-5f);
  __bf16* orow = out + (size_t)blockIdx.x * C;
  for (int i = threadIdx.x; i < C; i += 256) {
    float y = ((float)xr[i] - mean) * rs * g[i] + bb[i];
    if (do_silu) y = y / (1.f + __expf(-y));
    orow[i] = (__bf16)y;
  }
}

// ---------------------------------------------------------------------------
// MFMA attention v2, one (b,h) per 256-thread block, register softmax.
// LDS 49424B -> 3 blocks/CU (12 waves/CU). See R2 comments for layout proof.
// ---------------------------------------------------------------------------
__global__ __launch_bounds__(256)
void attn_mfma(const __bf16* __restrict__ qkv,
               const float* __restrict__ qg, const float* __restrict__ qb,
               const float* __restrict__ kg, const float* __restrict__ kb,
               const __bf16* __restrict__ bias, __bf16* __restrict__ o)
{
  __shared__ __align__(16) char smem[49424];
  __bf16* qs = (__bf16*)smem;               // [96][64]
  __bf16* ks = (__bf16*)(smem + 12288);     // [96][64]
  __bf16* Ps = (__bf16*)smem;               // [96][128] alias
  __bf16* vt = (__bf16*)(smem + 24576);     // [64][128]
  __bf16* bl = (__bf16*)(smem + 40960);     // [4232]

  const int tid = threadIdx.x;
  const int bh  = blockIdx.x;
  const int b = bh / 12, h = bh % 12;
  const int w = tid >> 6, lane = tid & 63;
  const int l31 = lane & 31, l5 = lane >> 5;
  const int li = lane & 7, rg = lane >> 3;

  // ---- phase 1: stage bias (16B coalesced) + load q/k/v with fused LN ----
  const __bf16* bp = bias + (size_t)bh * 4232;
  for (int idx = tid; idx < 529; idx += 256)
    *(v8bf*)(bl + idx * 8) = *(const v8bf*)(bp + idx * 8);

  float qgv[8], qbv[8], kgv[8], kbv[8];
#pragma unroll
  for (int e = 0; e < 8; ++e) {
    qgv[e] = qg[li * 8 + e]; qbv[e] = qb[li * 8 + e];
    kgv[e] = kg[li * 8 + e]; kbv[e] = kb[li * 8 + e];
  }

  for (int n0 = 0; n0 < 65; n0 += 32) {
    int n = n0 + w * 8 + rg;
    if (n < 65) {
      const __bf16* src = qkv + ((size_t)(b * 65 + n)) * 2304 + h * 64 + li * 8;
      v8bf qv8 = *(const v8bf*)(src);
      v8bf kv8 = *(const v8bf*)(src + 768);
      v8bf vv8 = *(const v8bf*)(src + 1536);
      float qf[8], kf[8];
      float s1 = 0.f, s2 = 0.f, t1 = 0.f, t2 = 0.f;
#pragma unroll
      for (int e = 0; e < 8; ++e) {
        qf[e] = (float)qv8[e]; kf[e] = (float)kv8[e];
        s1 += qf[e]; s2 += qf[e] * qf[e];
        t1 += kf[e]; t2 += kf[e] * kf[e];
      }
#pragma unroll
      for (int d = 1; d < 8; d <<= 1) {
        s1 += __shfl_xor(s1, d); s2 += __shfl_xor(s2, d);
        t1 += __shfl_xor(t1, d); t2 += __shfl_xor(t2, d);
      }
      float qm = s1 * 0.015625f, qva = s2 * 0.015625f - qm * qm;
      float km = t1 * 0.015625f, kva = t2 * 0.015625f - km * km;
      float qrs = rsqrtf(qva + 1e-5f), krs = rsqrtf(kva + 1e-5f);
      v8bf qo, ko;
#pragma unroll
      for (int e = 0; e < 8; ++e) {
        qo[e] = (__bf16)(((qf[e] - qm) * qrs * qgv[e] + qbv[e]) * 0.125f);
        ko[e] = (__bf16)((kf[e] - km) * krs * kgv[e] + kbv[e]);
      }
      *(v8bf*)(qs + n * 64 + (li ^ (n & 7)) * 8) = qo;
      *(v8bf*)(ks + n * 64 + (li ^ (n & 7)) * 8) = ko;
#pragma unroll
      for (int e = 0; e < 8; ++e) {
        int d = li * 8 + e;
        int swz = (d & 7) ^ (d >> 3);
        vt[d * 128 + (((n >> 3) ^ swz) * 8) + (n & 7)] = vv8[e];
      }
    }
  }
  // zero vt cols 65..95
  for (int e2 = tid; e2 < 64 * 31; e2 += 256) {
    int d = e2 / 31, j = 65 + e2 % 31;
    int swz = (d & 7) ^ (d >> 3);
    vt[d * 128 + (((j >> 3) ^ swz) * 8) + (j & 7)] = (__bf16)0.f;
  }
  __syncthreads();

  // ---- phase 2: QK^T, wave w owns row band it=w (waves 0..2) ----
  v16f s0 = {}, s1v = {}, s2v = {};
  if (w < 3) {
    const int mrow = w * 32 + l31;
#pragma unroll
    for (int kk = 0; kk < 4; ++kk) {
      int lc = kk * 2 + l5;
      v8bf aq = *(const v8bf*)(qs + mrow * 64 + ((lc ^ (mrow & 7)) * 8));
      v8bf b0 = *(const v8bf*)(ks + (l31) * 64      + ((lc ^ ((l31) & 7)) * 8));
      v8bf b1 = *(const v8bf*)(ks + (32 + l31) * 64 + ((lc ^ ((32 + l31) & 7)) * 8));
      v8bf b2 = *(const v8bf*)(ks + (64 + l31) * 64 + ((lc ^ ((64 + l31) & 7)) * 8));
      s0  = mfma32(aq, b0, s0);
      s1v = mfma32(aq, b1, s1v);
      s2v = mfma32(aq, b2, s2v);
    }
  }
  __syncthreads();   // all QK LDS reads complete; Ps may overwrite qs/ks

  // ---- phase 3: bias add + register softmax + write P (bf16) ----
  if (w < 3) {
    const int j0 = l31, j1 = 32 + l31, j2 = 64 + l31;
#pragma unroll
    for (int r = 0; r < 16; ++r) {
      int i = w * 32 + 4 * l5 + (r & 3) + 8 * (r >> 2);
      float v0 = s0[r], v1 = s1v[r], v2 = s2v[r];
      if (i < 65) {
        v0 += (float)bl[i * 65 + j0];
        v1 += (float)bl[i * 65 + j1];
        if (l31 == 0) v2 += (float)bl[i * 65 + 64];
      }
      float vx = (l31 == 0) ? v2 : -1e30f;
      float mx = fmaxf(fmaxf(v0, v1), vx);
#pragma unroll
      for (int d = 1; d < 32; d <<= 1) mx = fmaxf(mx, __shfl_xor(mx, d));
      float e0 = __expf(v0 - mx);
      float e1 = __expf(v1 - mx);
      float e2 = (l31 == 0) ? __expf(v2 - mx) : 0.f;
      float sum = e0 + e1 + e2;
#pragma unroll
      for (int d = 1; d < 32; d <<= 1) sum += __shfl_xor(sum, d);
      float inv = 1.f / sum;
      Ps[i * 128 + (((j0 >> 3) ^ (i & 7)) * 8) + (j0 & 7)] = (__bf16)(e0 * inv);
      Ps[i * 128 + (((j1 >> 3) ^ (i & 7)) * 8) + (j1 & 7)] = (__bf16)(e1 * inv);
      Ps[i * 128 + (((j2 >> 3) ^ (i & 7)) * 8) + (j2 & 7)] =
          (__bf16)((l31 == 0) ? e2 * inv : 0.f);
    }
  }
  __syncthreads();

  // ---- phase 4: O = P @ V, 6 tiles over 4 waves ----
  const int nt = (w < 2) ? 2 : 1;
  for (int tt = 0; tt < nt; ++tt) {
    int t = w + tt * 4;
    int it = t >> 1, dt = t & 1;
    int prow = it * 32 + l31;
    int drow = dt * 32 + l31;
    int dswz = (drow & 7) ^ (drow >> 3);
    v16f acc = {};
#pragma unroll
    for (int kk = 0; kk < 6; ++kk) {
      int lc = kk * 2 + l5;
      v8bf ap = *(const v8bf*)(Ps + prow * 128 + ((lc ^ (prow & 7)) * 8));
      v8bf bv = *(const v8bf*)(vt + drow * 128 + ((lc ^ dswz) * 8));
      acc = mfma32(ap, bv, acc);
    }
    int dcol = dt * 32 + l31;
#pragma unroll
    for (int r = 0; r < 16; ++r) {
      int i = it * 32 + 4 * l5 + (r & 3) + 8 * (r >> 2);
      if (i < 65)
        o[((size_t)(b * 65 + i) * 12 + h) * 64 + dcol] = (__bf16)acc[r];
    }
  }
}

extern "C" void kernel_launch(void* const* d_in, const int* in_sizes, int n_in,
                              void* d_out, int out_size, void* d_ws, size_t ws_size,
                              hipStream_t stream)
{
  (void)in_sizes; (void)n_in; (void)ws_size;
  const float* x_in    = (const float*)d_in[0];
  const float* ln1_g   = (const float*)d_in[1];
  const float* ln1_b   = (const float*)d_in[2];
  const float* qkv_w   = (const float*)d_in[3];
  const float* proj_w  = (const float*)d_in[4];
  const float* qn_g    = (const float*)d_in[5];
  const float* qn_b    = (const float*)d_in[6];
  const float* kn_g    = (const float*)d_in[7];
  const float* kn_b    = (const float*)d_in[8];
  const float* sg_w1   = (const float*)d_in[9];
  const float* sg_ln1g = (const float*)d_in[10];
  const float* sg_ln1b = (const float*)d_in[11];
  const float* sg_w2   = (const float*)d_in[12];
  const float* sg_ln2g = (const float*)d_in[13];
  const float* sg_ln2b = (const float*)d_in[14];
  const float* sg_bw   = (const float*)d_in[15];
  const float* ln2_g   = (const float*)d_in[16];
  const float* ln2_b   = (const float*)d_in[17];
  const float* gate_w  = (const float*)d_in[18];
  const float* value_w = (const float*)d_in[19];
  const float* out_w   = (const float*)d_in[20];

  char* ws = (char*)d_ws;
  size_t off = 0;
  auto alloc = [&](size_t bytes) -> char* {
    char* p = ws + off; off += (bytes + 255) & ~(size_t)255; return p;
  };

  // per-layer bf16 transposed weights (~25 MB total)
  __bf16* wt_qkv  = (__bf16*)alloc(2304ull * 768 * 2);
  __bf16* wt_proj = (__bf16*)alloc(768ull * 768 * 2);
  __bf16* wt_sg1  = (__bf16*)alloc(512ull * 768 * 2);
  __bf16* wt_sg2  = (__bf16*)alloc(3072ull * 512 * 2);
  __bf16* wt_bias = (__bf16*)alloc(4352ull * 256 * 2);
  __bf16* wt_gate = (__bf16*)alloc(3072ull * 768 * 2);
  __bf16* wt_val  = (__bf16*)alloc(3072ull * 768 * 2);
  __bf16* wt_out  = (__bf16*)alloc(768ull * 3072 * 2);
  // activations
  __bf16* hbuf    = (__bf16*)alloc(33280ull * 768 * 2);   // h / o / h2  (51 MB)
  __bf16* biasbuf = (__bf16*)alloc(6144ull * 4232 * 2);   // attn bias, stride 4232
  __bf16* BIG     = (__bf16*)alloc(33280ull * 2304 * 2);  // qkv         (153 MB)
  __bf16* t1buf   = (__bf16*)alloc(512ull * 512 * 2);
  __bf16* lat1    = (__bf16*)alloc(512ull * 512 * 2);
  __bf16* t2buf   = (__bf16*)alloc(512ull * 3072 * 2);
  __bf16* lat2    = (__bf16*)alloc(512ull * 3072 * 2);

  __bf16* qkvbuf = BIG;      // 33280 x 2304
  // MLP buffer 33280x3072 bf16 (204.5 MB) aliases biasbuf+BIG (205.3 MB
  // contiguous). Both bias and qkv are dead once attention has run.
  __bf16* mlpbuf = biasbuf;

  hipMemcpyAsync(d_out, x_in, (size_t)out_size * sizeof(float),
                 hipMemcpyDeviceToDevice, stream);
  float* xb = (float*)d_out;

  dim3 tb(32, 8);
  for (int l = 0; l < 6; ++l) {
    const float* l1g = ln1_g + l * 768;
    const float* l1b = ln1_b + l * 768;
    const float* qg  = qn_g + l * 64;
    const float* qb  = qn_b + l * 64;
    const float* kg  = kn_g + l * 64;
    const float* kb  = kn_b + l * 64;
    const float* s1g = sg_ln1g + l * 512;
    const float* s1b = sg_ln1b + l * 512;
    const float* s2g = sg_ln2g + l * 3072;
    const float* s2b = sg_ln2b + l * 3072;
    const float* l2g = ln2_g + l * 768;
    const float* l2b = ln2_b + l * 768;

    // stage this layer's weights as bf16 N x K — one batched launch
    TBatch tbat;
    const float* srcs[8] = {
      qkv_w  + (size_t)l * 768 * 2304, proj_w + (size_t)l * 768 * 768,
      sg_w1  + (size_t)l * 768 * 512,  sg_w2  + (size_t)l * 512 * 3072,
      sg_bw  + (size_t)l * 256 * 4225, gate_w + (size_t)l * 768 * 3072,
      value_w+ (size_t)l * 768 * 3072, out_w  + (size_t)l * 3072 * 768 };
    __bf16* dsts[8] = { wt_qkv, wt_proj, wt_sg1, wt_sg2, wt_bias,
                        wt_gate, wt_val, wt_out };
    const int Ks[8]  = {768, 768, 768, 512, 256, 768, 768, 3072};
    const int Ns[8]  = {2304, 768, 512, 3072, 4225, 3072, 3072, 768};
    const int Nps[8] = {2304, 768, 512, 3072, 4352, 3072, 3072, 768};
    int blk = 0;
    for (int s = 0; s < 8; ++s) {
      tbat.src[s] = srcs[s]; tbat.dst[s] = dsts[s];
      tbat.K[s] = Ks[s]; tbat.N[s] = Ns[s]; tbat.Npad[s] = Nps[s];
      tbat.gx[s] = Nps[s] / 32;
      tbat.blk0[s] = blk;
      blk += (Nps[s] / 32) * ((Ks[s] + 31) / 32);
    }
    transpose_batched<<<blk, tb, 0, stream>>>(tbat);

    // LN1: x -> h (bf16)
    ln768_f32_to_bf16<<<8320, 256, 0, stream>>>(xb, l1g, l1b, hbuf);
    // qkv = h @ Wqkv  (33280 x 2304)
    gemm_bt<EPI_BF16><<<dim3(18, 260), 256, 0, stream>>>(
        hbuf, 768, wt_qkv, qkvbuf, nullptr, 2304, 768, 2304);
    // cls path: t1 = cls @ w1 (cls rows = h[b*65], lda = 65*768)
    gemm_bt<EPI_BF16><<<dim3(4, 4), 256, 0, stream>>>(
        hbuf, 65 * 768, wt_sg1, t1buf, nullptr, 512, 768, 512);
    ln_bf16_kernel<<<512, 256, 0, stream>>>(t1buf, s1g, s1b, lat1, 512, 1);
    gemm_bt<EPI_BF16><<<dim3(24, 4), 256, 0, stream>>>(
        lat1, 512, wt_sg2, t2buf, nullptr, 3072, 512, 3072);
    ln_bf16_kernel<<<512, 256, 0, stream>>>(t2buf, s2g, s2b, lat2, 3072, 0);
    // bias = lat2 (6144 x 256) @ bw^T (4352 x 256), masked to 4225 cols,
    // compacted to stride 4232 (16B rows for coalesced LDS staging in attn)
    gemm_bt<EPI_BF16MASK><<<dim3(34, 48), 256, 0, stream>>>(
        lat2, 256, wt_bias, biasbuf, nullptr, 4352, 256, 4225);
    // fused MFMA attention (q/k LN inside) -> o into hbuf
    attn_mfma<<<6144, 256, 0, stream>>>(qkvbuf, qg, qb, kg, kb, biasbuf, hbuf);
    // x += o @ Wproj
    gemm_bt<EPI_ADDF32><<<dim3(6, 260), 256, 0, stream>>>(
        hbuf, 768, wt_proj, xb, nullptr, 768, 768, 768);
    // LN2: x -> h2 (reuses hbuf)
    ln768_f32_to_bf16<<<8320, 256, 0, stream>>>(xb, l2g, l2b, hbuf);
    // fused gated MLP: mlp = silu(h2@Wv^T) * (h2@Wg^T), single dispatch
    gemm_mlp<<<dim3(24, 260), 256, 0, stream>>>(
        hbuf, wt_val, wt_gate, mlpbuf, 3072, 768);
    // x += mlp @ Wout
    gemm_bt<EPI_ADDF32><<<dim3(6, 260), 256, 0, stream>>>(
        mlpbuf, 3072, wt_out, xb, nullptr, 768, 3072, 768);
  }
}

// Round 4
// 8076.427 us; speedup vs baseline: 1.1739x; 1.1739x over previous
//
#include <hip/hip_runtime.h>
#include <hip/hip_bf16.h>

// ---------------------------------------------------------------------------
// ViTChess: 6-layer transformer block stack, B=512 N=65 C=768 H=12 DH=64
// bf16 MFMA GEMMs (32x32x16), fp32 accum, residual stream lives in d_out.
// R4: revert R3's xcd_remap + occ5 (isolated regression); keep fused MLP
//     GEMM (verified -105us/layer) and batched weight transposes.
// ---------------------------------------------------------------------------

typedef __bf16 v8bf  __attribute__((ext_vector_type(8)));
typedef __bf16 v4bf  __attribute__((ext_vector_type(4)));
typedef float  v16f  __attribute__((ext_vector_type(16)));

#define EPI_BF16      0
#define EPI_ADDF32    1
#define EPI_SILU      2
#define EPI_MUL       3
#define EPI_BF16MASK  4

__device__ __forceinline__ v16f mfma32(v8bf a, v8bf b, v16f c) {
  return __builtin_amdgcn_mfma_f32_32x32x16_bf16(a, b, c, 0, 0, 0);
}

// C[M,N] = A[M,K] @ Bt[N,K]^T.  M%128==0, N%128==0 (padded), K%64==0.
// LDS tiles 128x64 bf16, 16B chunks XOR-swizzled by (row&7). 3 blocks/CU.
template<int EPI>
__global__ __launch_bounds__(256, 3)
void gemm_bt(const __bf16* __restrict__ A, long long lda,
             const __bf16* __restrict__ Bt,
             void* outp, const __bf16* extra,
             int Nout, int K, int nvalid)
{
  __shared__ __align__(16) __bf16 Als[128 * 64];
  __shared__ __align__(16) __bf16 Bls[128 * 64];
  const int tid  = threadIdx.x;
  const int w    = tid >> 6, lane = tid & 63;
  const int m0   = blockIdx.y * 128, n0 = blockIdx.x * 128;
  const int wm   = (w & 1) * 64, wn = (w >> 1) * 64;
  const int l31  = lane & 31, l5 = lane >> 5;

  const __bf16* ag[4];
  const __bf16* bg[4];
#pragma unroll
  for (int i = 0; i < 4; ++i) {
    int li  = i * 256 + tid;
    int row = li >> 3;
    int c   = (li & 7) ^ (row & 7);           // swizzled source chunk
    ag[i] = A  + (size_t)(m0 + row) * (size_t)lda + c * 8;
    bg[i] = Bt + (size_t)(n0 + row) * (size_t)K   + c * 8;
  }
  char* alds0 = ((char*)Als) + w * 1024;
  char* blds0 = ((char*)Bls) + w * 1024;

  v16f acc[2][2] = {};

  for (int kt = 0; kt < K; kt += 64) {
#pragma unroll
    for (int i = 0; i < 4; ++i) {
      __builtin_amdgcn_global_load_lds(
          (const __attribute__((address_space(1))) void*)(ag[i]),
          (__attribute__((address_space(3))) void*)(alds0 + i * 4096), 16, 0, 0);
      __builtin_amdgcn_global_load_lds(
          (const __attribute__((address_space(1))) void*)(bg[i]),
          (__attribute__((address_space(3))) void*)(blds0 + i * 4096), 16, 0, 0);
      ag[i] += 64; bg[i] += 64;
    }
    __syncthreads();
#pragma unroll
    for (int kk = 0; kk < 4; ++kk) {
      v8bf af[2], bf[2];
#pragma unroll
      for (int t = 0; t < 2; ++t) {
        int m  = wm + t * 32 + l31;
        int ch = (kk * 2 + l5) ^ (m & 7);
        af[t] = *(const v8bf*)(Als + m * 64 + ch * 8);
        int n   = wn + t * 32 + l31;
        int ch2 = (kk * 2 + l5) ^ (n & 7);
        bf[t] = *(const v8bf*)(Bls + n * 64 + ch2 * 8);
      }
      acc[0][0] = mfma32(af[0], bf[0], acc[0][0]);
      acc[0][1] = mfma32(af[0], bf[1], acc[0][1]);
      acc[1][0] = mfma32(af[1], bf[0], acc[1][0]);
      acc[1][1] = mfma32(af[1], bf[1], acc[1][1]);
    }
    __syncthreads();
  }

  // D layout: col = lane&31, row = (r&3) + 8*(r>>2) + 4*(lane>>5)
#pragma unroll
  for (int mi = 0; mi < 2; ++mi)
#pragma unroll
  for (int ni = 0; ni < 2; ++ni) {
    int col  = n0 + wn + ni * 32 + l31;
    int rowb = m0 + wm + mi * 32 + 4 * l5;
#pragma unroll
    for (int r = 0; r < 16; ++r) {
      int row   = rowb + (r & 3) + 8 * (r >> 2);
      float val = acc[mi][ni][r];
      size_t idx = (size_t)row * (size_t)Nout + col;
      if (EPI == EPI_BF16) {
        ((__bf16*)outp)[idx] = (__bf16)val;
      } else if (EPI == EPI_ADDF32) {
        ((float*)outp)[idx] += val;
      } else if (EPI == EPI_SILU) {
        float s = val / (1.f + __expf(-val));
        ((__bf16*)outp)[idx] = (__bf16)s;
      } else if (EPI == EPI_MUL) {
        float e = (float)extra[idx];
        ((__bf16*)outp)[idx] = (__bf16)(val * e);
      } else { // EPI_BF16MASK: output compacted to stride (nvalid+7)&~7
        int stride = (nvalid + 7) & ~7;
        if (col < nvalid)
          ((__bf16*)outp)[(size_t)row * (size_t)stride + col] = (__bf16)val;
      }
    }
  }
}

// Fused MLP: out[M,N] = silu(A@Bv^T) * (A@Bg^T), bf16 out. A staged once.
// LDS 48KB -> 3 blocks/CU.
__global__ __launch_bounds__(256, 3)
void gemm_mlp(const __bf16* __restrict__ A,
              const __bf16* __restrict__ Bv, const __bf16* __restrict__ Bg,
              __bf16* __restrict__ outp, int Nout, int K)
{
  __shared__ __align__(16) __bf16 Als [128 * 64];
  __shared__ __align__(16) __bf16 Bvls[128 * 64];
  __shared__ __align__(16) __bf16 Bgls[128 * 64];
  const int tid  = threadIdx.x;
  const int w    = tid >> 6, lane = tid & 63;
  const int m0   = blockIdx.y * 128, n0 = blockIdx.x * 128;
  const int wm   = (w & 1) * 64, wn = (w >> 1) * 64;
  const int l31  = lane & 31, l5 = lane >> 5;

  const __bf16* ag[4];
  const __bf16* bvg[4];
  const __bf16* bgg[4];
#pragma unroll
  for (int i = 0; i < 4; ++i) {
    int li  = i * 256 + tid;
    int row = li >> 3;
    int c   = (li & 7) ^ (row & 7);
    ag[i]  = A  + (size_t)(m0 + row) * (size_t)K + c * 8;
    bvg[i] = Bv + (size_t)(n0 + row) * (size_t)K + c * 8;
    bgg[i] = Bg + (size_t)(n0 + row) * (size_t)K + c * 8;
  }
  char* alds0  = ((char*)Als)  + w * 1024;
  char* bvlds0 = ((char*)Bvls) + w * 1024;
  char* bglds0 = ((char*)Bgls) + w * 1024;

  v16f accv[2][2] = {};
  v16f accg[2][2] = {};

  for (int kt = 0; kt < K; kt += 64) {
#pragma unroll
    for (int i = 0; i < 4; ++i) {
      __builtin_amdgcn_global_load_lds(
          (const __attribute__((address_space(1))) void*)(ag[i]),
          (__attribute__((address_space(3))) void*)(alds0 + i * 4096), 16, 0, 0);
      __builtin_amdgcn_global_load_lds(
          (const __attribute__((address_space(1))) void*)(bvg[i]),
          (__attribute__((address_space(3))) void*)(bvlds0 + i * 4096), 16, 0, 0);
      __builtin_amdgcn_global_load_lds(
          (const __attribute__((address_space(1))) void*)(bgg[i]),
          (__attribute__((address_space(3))) void*)(bglds0 + i * 4096), 16, 0, 0);
      ag[i] += 64; bvg[i] += 64; bgg[i] += 64;
    }
    __syncthreads();
#pragma unroll
    for (int kk = 0; kk < 4; ++kk) {
      v8bf af[2], bv[2], bg2[2];
#pragma unroll
      for (int t = 0; t < 2; ++t) {
        int m  = wm + t * 32 + l31;
        int ch = (kk * 2 + l5) ^ (m & 7);
        af[t] = *(const v8bf*)(Als + m * 64 + ch * 8);
        int n   = wn + t * 32 + l31;
        int ch2 = (kk * 2 + l5) ^ (n & 7);
        bv[t]  = *(const v8bf*)(Bvls + n * 64 + ch2 * 8);
        bg2[t] = *(const v8bf*)(Bgls + n * 64 + ch2 * 8);
      }
      accv[0][0] = mfma32(af[0], bv[0],  accv[0][0]);
      accg[0][0] = mfma32(af[0], bg2[0], accg[0][0]);
      accv[0][1] = mfma32(af[0], bv[1],  accv[0][1]);
      accg[0][1] = mfma32(af[0], bg2[1], accg[0][1]);
      accv[1][0] = mfma32(af[1], bv[0],  accv[1][0]);
      accg[1][0] = mfma32(af[1], bg2[0], accg[1][0]);
      accv[1][1] = mfma32(af[1], bv[1],  accv[1][1]);
      accg[1][1] = mfma32(af[1], bg2[1], accg[1][1]);
    }
    __syncthreads();
  }

#pragma unroll
  for (int mi = 0; mi < 2; ++mi)
#pragma unroll
  for (int ni = 0; ni < 2; ++ni) {
    int col  = n0 + wn + ni * 32 + l31;
    int rowb = m0 + wm + mi * 32 + 4 * l5;
#pragma unroll
    for (int r = 0; r < 16; ++r) {
      int row = rowb + (r & 3) + 8 * (r >> 2);
      float v = accv[mi][ni][r];
      float g = accg[mi][ni][r];
      float s = v / (1.f + __expf(-v)) * g;
      outp[(size_t)row * (size_t)Nout + col] = (__bf16)s;
    }
  }
}

// Batched fp32 (K,N) -> bf16 (Npad,K) transpose; 8 segments in one launch.
struct TBatch {
  const float* src[8];
  __bf16* dst[8];
  int K[8], N[8], Npad[8], gx[8], blk0[8];
};

__global__ void transpose_batched(TBatch tb)
{
  __shared__ float t[32][33];
  int id = blockIdx.x;
  int s = 0;
#pragma unroll
  for (int i = 1; i < 8; ++i) if (id >= tb.blk0[i]) s = i;
  const float* src = tb.src[s];
  __bf16* dst = tb.dst[s];
  const int K = tb.K[s], N = tb.N[s], Npad = tb.Npad[s];
  int local = id - tb.blk0[s];
  int bx = local % tb.gx[s], by = local / tb.gx[s];
  int n0 = bx * 32, k0 = by * 32;
  int tx = threadIdx.x, ty = threadIdx.y;
#pragma unroll
  for (int i = 0; i < 32; i += 8) {
    int k = k0 + ty + i, n = n0 + tx;
    t[ty + i][tx] = (k < K && n < N) ? src[(size_t)k * N + n] : 0.f;
  }
  __syncthreads();
#pragma unroll
  for (int i = 0; i < 32; i += 8) {
    int n = n0 + ty + i, k = k0 + tx;
    if (n < Npad && k < K) dst[(size_t)n * K + k] = (__bf16)t[tx][ty + i];
  }
}

// row LN fp32->bf16, C=768, one wave per row, 4 rows per block (float4 loads)
__global__ __launch_bounds__(256)
void ln768_f32_to_bf16(const float* __restrict__ x, const float* __restrict__ g,
                       const float* __restrict__ bb, __bf16* __restrict__ out)
{
  const int row  = blockIdx.x * 4 + (threadIdx.x >> 6);
  const int lane = threadIdx.x & 63;
  const float* xr = x + (size_t)row * 768;
  float4 v[3];
  float sum = 0.f, sq = 0.f;
#pragma unroll
  for (int c = 0; c < 3; ++c) {
    v[c] = *(const float4*)(xr + c * 256 + lane * 4);
    sum += v[c].x + v[c].y + v[c].z + v[c].w;
    sq  += v[c].x * v[c].x + v[c].y * v[c].y + v[c].z * v[c].z + v[c].w * v[c].w;
  }
#pragma unroll
  for (int d = 1; d < 64; d <<= 1) { sum += __shfl_xor(sum, d); sq += __shfl_xor(sq, d); }
  float mean = sum * (1.f / 768.f);
  float var  = sq * (1.f / 768.f) - mean * mean;
  float rs   = rsqrtf(var + 1e-5f);
  __bf16* orow = out + (size_t)row * 768;
#pragma unroll
  for (int c = 0; c < 3; ++c) {
    float4 gv = *(const float4*)(g  + c * 256 + lane * 4);
    float4 bv = *(const float4*)(bb + c * 256 + lane * 4);
    v4bf o4;
    o4[0] = (__bf16)((v[c].x - mean) * rs * gv.x + bv.x);
    o4[1] = (__bf16)((v[c].y - mean) * rs * gv.y + bv.y);
    o4[2] = (__bf16)((v[c].z - mean) * rs * gv.z + bv.z);
    o4[3] = (__bf16)((v[c].w - mean) * rs * gv.w + bv.w);
    *(v4bf*)(orow + c * 256 + lane * 4) = o4;
  }
}

// row LN on bf16 input, optional silu (cls path, small)
__global__ __launch_bounds__(256)
void ln_bf16_kernel(const __bf16* __restrict__ x, const float* __restrict__ g,
                    const float* __restrict__ bb, __bf16* __restrict__ out,
                    int C, int do_silu)
{
  __shared__ float sm[8];
  const __bf16* xr = x + (size_t)blockIdx.x * C;
  float sum = 0.f, sq = 0.f;
  for (int i = threadIdx.x; i < C; i += 256) { float v = (float)xr[i]; sum += v; sq += v * v; }
#pragma unroll
  for (int d = 1; d < 64; d <<= 1) { sum += __shfl_xor(sum, d); sq += __shfl_xor(sq, d); }
  if ((threadIdx.x & 63) == 0) { sm[threadIdx.x >> 6] = sum; sm[4 + (threadIdx.x >> 6)] = sq; }
  __syncthreads();
  sum = sm[0] + sm[1] + sm[2] + sm[3];
  sq  = sm[4] + sm[5] + sm[6] + sm[7];
  float mean = sum / C;
  float var  = sq / C - mean * mean;
  float rs   = rsqrtf(var + 1e-5f);
  __bf16* orow = out + (size_t)blockIdx.x * C;
  for (int i = threadIdx.x; i < C; i += 256) {
    float y = ((float)xr[i] - mean) * rs * g[i] + bb[i];
    if (do_silu) y = y / (1.f + __expf(-y));
    orow[i] = (__bf16)y;
  }
}

// ---------------------------------------------------------------------------
// MFMA attention v2, one (b,h) per 256-thread block, register softmax.
// LDS 49424B -> 3 blocks/CU (12 waves/CU). See R2 comments for layout proof.
// ---------------------------------------------------------------------------
__global__ __launch_bounds__(256)
void attn_mfma(const __bf16* __restrict__ qkv,
               const float* __restrict__ qg, const float* __restrict__ qb,
               const float* __restrict__ kg, const float* __restrict__ kb,
               const __bf16* __restrict__ bias, __bf16* __restrict__ o)
{
  __shared__ __align__(16) char smem[49424];
  __bf16* qs = (__bf16*)smem;               // [96][64]
  __bf16* ks = (__bf16*)(smem + 12288);     // [96][64]
  __bf16* Ps = (__bf16*)smem;               // [96][128] alias
  __bf16* vt = (__bf16*)(smem + 24576);     // [64][128]
  __bf16* bl = (__bf16*)(smem + 40960);     // [4232]

  const int tid = threadIdx.x;
  const int bh  = blockIdx.x;
  const int b = bh / 12, h = bh % 12;
  const int w = tid >> 6, lane = tid & 63;
  const int l31 = lane & 31, l5 = lane >> 5;
  const int li = lane & 7, rg = lane >> 3;

  // ---- phase 1: stage bias (16B coalesced) + load q/k/v with fused LN ----
  const __bf16* bp = bias + (size_t)bh * 4232;
  for (int idx = tid; idx < 529; idx += 256)
    *(v8bf*)(bl + idx * 8) = *(const v8bf*)(bp + idx * 8);

  float qgv[8], qbv[8], kgv[8], kbv[8];
#pragma unroll
  for (int e = 0; e < 8; ++e) {
    qgv[e] = qg[li * 8 + e]; qbv[e] = qb[li * 8 + e];
    kgv[e] = kg[li * 8 + e]; kbv[e] = kb[li * 8 + e];
  }

  for (int n0 = 0; n0 < 65; n0 += 32) {
    int n = n0 + w * 8 + rg;
    if (n < 65) {
      const __bf16* src = qkv + ((size_t)(b * 65 + n)) * 2304 + h * 64 + li * 8;
      v8bf qv8 = *(const v8bf*)(src);
      v8bf kv8 = *(const v8bf*)(src + 768);
      v8bf vv8 = *(const v8bf*)(src + 1536);
      float qf[8], kf[8];
      float s1 = 0.f, s2 = 0.f, t1 = 0.f, t2 = 0.f;
#pragma unroll
      for (int e = 0; e < 8; ++e) {
        qf[e] = (float)qv8[e]; kf[e] = (float)kv8[e];
        s1 += qf[e]; s2 += qf[e] * qf[e];
        t1 += kf[e]; t2 += kf[e] * kf[e];
      }
#pragma unroll
      for (int d = 1; d < 8; d <<= 1) {
        s1 += __shfl_xor(s1, d); s2 += __shfl_xor(s2, d);
        t1 += __shfl_xor(t1, d); t2 += __shfl_xor(t2, d);
      }
      float qm = s1 * 0.015625f, qva = s2 * 0.015625f - qm * qm;
      float km = t1 * 0.015625f, kva = t2 * 0.015625f - km * km;
      float qrs = rsqrtf(qva + 1e-5f), krs = rsqrtf(kva + 1e-5f);
      v8bf qo, ko;
#pragma unroll
      for (int e = 0; e < 8; ++e) {
        qo[e] = (__bf16)(((qf[e] - qm) * qrs * qgv[e] + qbv[e]) * 0.125f);
        ko[e] = (__bf16)((kf[e] - km) * krs * kgv[e] + kbv[e]);
      }
      *(v8bf*)(qs + n * 64 + (li ^ (n & 7)) * 8) = qo;
      *(v8bf*)(ks + n * 64 + (li ^ (n & 7)) * 8) = ko;
#pragma unroll
      for (int e = 0; e < 8; ++e) {
        int d = li * 8 + e;
        int swz = (d & 7) ^ (d >> 3);
        vt[d * 128 + (((n >> 3) ^ swz) * 8) + (n & 7)] = vv8[e];
      }
    }
  }
  // zero vt cols 65..95
  for (int e2 = tid; e2 < 64 * 31; e2 += 256) {
    int d = e2 / 31, j = 65 + e2 % 31;
    int swz = (d & 7) ^ (d >> 3);
    vt[d * 128 + (((j >> 3) ^ swz) * 8) + (j & 7)] = (__bf16)0.f;
  }
  __syncthreads();

  // ---- phase 2: QK^T, wave w owns row band it=w (waves 0..2) ----
  v16f s0 = {}, s1v = {}, s2v = {};
  if (w < 3) {
    const int mrow = w * 32 + l31;
#pragma unroll
    for (int kk = 0; kk < 4; ++kk) {
      int lc = kk * 2 + l5;
      v8bf aq = *(const v8bf*)(qs + mrow * 64 + ((lc ^ (mrow & 7)) * 8));
      v8bf b0 = *(const v8bf*)(ks + (l31) * 64      + ((lc ^ ((l31) & 7)) * 8));
      v8bf b1 = *(const v8bf*)(ks + (32 + l31) * 64 + ((lc ^ ((32 + l31) & 7)) * 8));
      v8bf b2 = *(const v8bf*)(ks + (64 + l31) * 64 + ((lc ^ ((64 + l31) & 7)) * 8));
      s0  = mfma32(aq, b0, s0);
      s1v = mfma32(aq, b1, s1v);
      s2v = mfma32(aq, b2, s2v);
    }
  }
  __syncthreads();   // all QK LDS reads complete; Ps may overwrite qs/ks

  // ---- phase 3: bias add + register softmax + write P (bf16) ----
  if (w < 3) {
    const int j0 = l31, j1 = 32 + l31, j2 = 64 + l31;
#pragma unroll
    for (int r = 0; r < 16; ++r) {
      int i = w * 32 + 4 * l5 + (r & 3) + 8 * (r >> 2);
      float v0 = s0[r], v1 = s1v[r], v2 = s2v[r];
      if (i < 65) {
        v0 += (float)bl[i * 65 + j0];
        v1 += (float)bl[i * 65 + j1];
        if (l31 == 0) v2 += (float)bl[i * 65 + 64];
      }
      float vx = (l31 == 0) ? v2 : -1e30f;
      float mx = fmaxf(fmaxf(v0, v1), vx);
#pragma unroll
      for (int d = 1; d < 32; d <<= 1) mx = fmaxf(mx, __shfl_xor(mx, d));
      float e0 = __expf(v0 - mx);
      float e1 = __expf(v1 - mx);
      float e2 = (l31 == 0) ? __expf(v2 - mx) : 0.f;
      float sum = e0 + e1 + e2;
#pragma unroll
      for (int d = 1; d < 32; d <<= 1) sum += __shfl_xor(sum, d);
      float inv = 1.f / sum;
      Ps[i * 128 + (((j0 >> 3) ^ (i & 7)) * 8) + (j0 & 7)] = (__bf16)(e0 * inv);
      Ps[i * 128 + (((j1 >> 3) ^ (i & 7)) * 8) + (j1 & 7)] = (__bf16)(e1 * inv);
      Ps[i * 128 + (((j2 >> 3) ^ (i & 7)) * 8) + (j2 & 7)] =
          (__bf16)((l31 == 0) ? e2 * inv : 0.f);
    }
  }
  __syncthreads();

  // ---- phase 4: O = P @ V, 6 tiles over 4 waves ----
  const int nt = (w < 2) ? 2 : 1;
  for (int tt = 0; tt < nt; ++tt) {
    int t = w + tt * 4;
    int it = t >> 1, dt = t & 1;
    int prow = it * 32 + l31;
    int drow = dt * 32 + l31;
    int dswz = (drow & 7) ^ (drow >> 3);
    v16f acc = {};
#pragma unroll
    for (int kk = 0; kk < 6; ++kk) {
      int lc = kk * 2 + l5;
      v8bf ap = *(const v8bf*)(Ps + prow * 128 + ((lc ^ (prow & 7)) * 8));
      v8bf bv = *(const v8bf*)(vt + drow * 128 + ((lc ^ dswz) * 8));
      acc = mfma32(ap, bv, acc);
    }
    int dcol = dt * 32 + l31;
#pragma unroll
    for (int r = 0; r < 16; ++r) {
      int i = it * 32 + 4 * l5 + (r & 3) + 8 * (r >> 2);
      if (i < 65)
        o[((size_t)(b * 65 + i) * 12 + h) * 64 + dcol] = (__bf16)acc[r];
    }
  }
}

extern "C" void kernel_launch(void* const* d_in, const int* in_sizes, int n_in,
                              void* d_out, int out_size, void* d_ws, size_t ws_size,
                              hipStream_t stream)
{
  (void)in_sizes; (void)n_in; (void)ws_size;
  const float* x_in    = (const float*)d_in[0];
  const float* ln1_g   = (const float*)d_in[1];
  const float* ln1_b   = (const float*)d_in[2];
  const float* qkv_w   = (const float*)d_in[3];
  const float* proj_w  = (const float*)d_in[4];
  const float* qn_g    = (const float*)d_in[5];
  const float* qn_b    = (const float*)d_in[6];
  const float* kn_g    = (const float*)d_in[7];
  const float* kn_b    = (const float*)d_in[8];
  const float* sg_w1   = (const float*)d_in[9];
  const float* sg_ln1g = (const float*)d_in[10];
  const float* sg_ln1b = (const float*)d_in[11];
  const float* sg_w2   = (const float*)d_in[12];
  const float* sg_ln2g = (const float*)d_in[13];
  const float* sg_ln2b = (const float*)d_in[14];
  const float* sg_bw   = (const float*)d_in[15];
  const float* ln2_g   = (const float*)d_in[16];
  const float* ln2_b   = (const float*)d_in[17];
  const float* gate_w  = (const float*)d_in[18];
  const float* value_w = (const float*)d_in[19];
  const float* out_w   = (const float*)d_in[20];

  char* ws = (char*)d_ws;
  size_t off = 0;
  auto alloc = [&](size_t bytes) -> char* {
    char* p = ws + off; off += (bytes + 255) & ~(size_t)255; return p;
  };

  // per-layer bf16 transposed weights (~25 MB total)
  __bf16* wt_qkv  = (__bf16*)alloc(2304ull * 768 * 2);
  __bf16* wt_proj = (__bf16*)alloc(768ull * 768 * 2);
  __bf16* wt_sg1  = (__bf16*)alloc(512ull * 768 * 2);
  __bf16* wt_sg2  = (__bf16*)alloc(3072ull * 512 * 2);
  __bf16* wt_bias = (__bf16*)alloc(4352ull * 256 * 2);
  __bf16* wt_gate = (__bf16*)alloc(3072ull * 768 * 2);
  __bf16* wt_val  = (__bf16*)alloc(3072ull * 768 * 2);
  __bf16* wt_out  = (__bf16*)alloc(768ull * 3072 * 2);
  // activations
  __bf16* hbuf    = (__bf16*)alloc(33280ull * 768 * 2);   // h / o / h2  (51 MB)
  __bf16* biasbuf = (__bf16*)alloc(6144ull * 4232 * 2);   // attn bias, stride 4232
  __bf16* BIG     = (__bf16*)alloc(33280ull * 2304 * 2);  // qkv         (153 MB)
  __bf16* t1buf   = (__bf16*)alloc(512ull * 512 * 2);
  __bf16* lat1    = (__bf16*)alloc(512ull * 512 * 2);
  __bf16* t2buf   = (__bf16*)alloc(512ull * 3072 * 2);
  __bf16* lat2    = (__bf16*)alloc(512ull * 3072 * 2);

  __bf16* qkvbuf = BIG;      // 33280 x 2304
  // MLP buffer 33280x3072 bf16 (204.5 MB) aliases biasbuf+BIG (205.3 MB
  // contiguous). Both bias and qkv are dead once attention has run.
  __bf16* mlpbuf = biasbuf;

  hipMemcpyAsync(d_out, x_in, (size_t)out_size * sizeof(float),
                 hipMemcpyDeviceToDevice, stream);
  float* xb = (float*)d_out;

  dim3 tb(32, 8);
  for (int l = 0; l < 6; ++l) {
    const float* l1g = ln1_g + l * 768;
    const float* l1b = ln1_b + l * 768;
    const float* qg  = qn_g + l * 64;
    const float* qb  = qn_b + l * 64;
    const float* kg  = kn_g + l * 64;
    const float* kb  = kn_b + l * 64;
    const float* s1g = sg_ln1g + l * 512;
    const float* s1b = sg_ln1b + l * 512;
    const float* s2g = sg_ln2g + l * 3072;
    const float* s2b = sg_ln2b + l * 3072;
    const float* l2g = ln2_g + l * 768;
    const float* l2b = ln2_b + l * 768;

    // stage this layer's weights as bf16 N x K — one batched launch
    TBatch tbat;
    const float* srcs[8] = {
      qkv_w  + (size_t)l * 768 * 2304, proj_w + (size_t)l * 768 * 768,
      sg_w1  + (size_t)l * 768 * 512,  sg_w2  + (size_t)l * 512 * 3072,
      sg_bw  + (size_t)l * 256 * 4225, gate_w + (size_t)l * 768 * 3072,
      value_w+ (size_t)l * 768 * 3072, out_w  + (size_t)l * 3072 * 768 };
    __bf16* dsts[8] = { wt_qkv, wt_proj, wt_sg1, wt_sg2, wt_bias,
                        wt_gate, wt_val, wt_out };
    const int Ks[8]  = {768, 768, 768, 512, 256, 768, 768, 3072};
    const int Ns[8]  = {2304, 768, 512, 3072, 4225, 3072, 3072, 768};
    const int Nps[8] = {2304, 768, 512, 3072, 4352, 3072, 3072, 768};
    int blk = 0;
    for (int s = 0; s < 8; ++s) {
      tbat.src[s] = srcs[s]; tbat.dst[s] = dsts[s];
      tbat.K[s] = Ks[s]; tbat.N[s] = Ns[s]; tbat.Npad[s] = Nps[s];
      tbat.gx[s] = Nps[s] / 32;
      tbat.blk0[s] = blk;
      blk += (Nps[s] / 32) * ((Ks[s] + 31) / 32);
    }
    transpose_batched<<<blk, tb, 0, stream>>>(tbat);

    // LN1: x -> h (bf16)
    ln768_f32_to_bf16<<<8320, 256, 0, stream>>>(xb, l1g, l1b, hbuf);
    // qkv = h @ Wqkv  (33280 x 2304)
    gemm_bt<EPI_BF16><<<dim3(18, 260), 256, 0, stream>>>(
        hbuf, 768, wt_qkv, qkvbuf, nullptr, 2304, 768, 2304);
    // cls path: t1 = cls @ w1 (cls rows = h[b*65], lda = 65*768)
    gemm_bt<EPI_BF16><<<dim3(4, 4), 256, 0, stream>>>(
        hbuf, 65 * 768, wt_sg1, t1buf, nullptr, 512, 768, 512);
    ln_bf16_kernel<<<512, 256, 0, stream>>>(t1buf, s1g, s1b, lat1, 512, 1);
    gemm_bt<EPI_BF16><<<dim3(24, 4), 256, 0, stream>>>(
        lat1, 512, wt_sg2, t2buf, nullptr, 3072, 512, 3072);
    ln_bf16_kernel<<<512, 256, 0, stream>>>(t2buf, s2g, s2b, lat2, 3072, 0);
    // bias = lat2 (6144 x 256) @ bw^T (4352 x 256), masked to 4225 cols,
    // compacted to stride 4232 (16B rows for coalesced LDS staging in attn)
    gemm_bt<EPI_BF16MASK><<<dim3(34, 48), 256, 0, stream>>>(
        lat2, 256, wt_bias, biasbuf, nullptr, 4352, 256, 4225);
    // fused MFMA attention (q/k LN inside) -> o into hbuf
    attn_mfma<<<6144, 256, 0, stream>>>(qkvbuf, qg, qb, kg, kb, biasbuf, hbuf);
    // x += o @ Wproj
    gemm_bt<EPI_ADDF32><<<dim3(6, 260), 256, 0, stream>>>(
        hbuf, 768, wt_proj, xb, nullptr, 768, 768, 768);
    // LN2: x -> h2 (reuses hbuf)
    ln768_f32_to_bf16<<<8320, 256, 0, stream>>>(xb, l2g, l2b, hbuf);
    // fused gated MLP: mlp = silu(h2@Wv^T) * (h2@Wg^T), single dispatch
    gemm_mlp<<<dim3(24, 260), 256, 0, stream>>>(
        hbuf, wt_val, wt_gate, mlpbuf, 3072, 768);
    // x += mlp @ Wout
    gemm_bt<EPI_ADDF32><<<dim3(6, 260), 256, 0, stream>>>(
        mlpbuf, 3072, wt_out, xb, nullptr, 768, 3072, 768);
  }
}